// Round 1
// baseline (439.089 us; speedup 1.0000x reference)
//
#include <hip/hip_runtime.h>
#include <math.h>

#define N 4096
#define DD 256
#define CAP 256
#define LEAKY 0.2f

// ---- monotone float<->uint map for atomicMax on floats ----
__device__ __forceinline__ unsigned fmap(float f){
  unsigned u = __float_as_uint(f);
  return (u & 0x80000000u) ? ~u : (u | 0x80000000u);
}
__device__ __forceinline__ float funmap(unsigned u){
  unsigned b = (u & 0x80000000u) ? (u & 0x7fffffffu) : ~u;
  return __uint_as_float(b);
}

// Pass A: per-column max of x = -cost  (coalesced slab streaming)
__global__ __launch_bounds__(256) void k_colmax(const float* __restrict__ cost,
                                                unsigned* __restrict__ colmax){
  int j  = blockIdx.x * 256 + threadIdx.x;
  int r0 = blockIdx.y * 128;
  const float* p = cost + (size_t)r0 * N + j;
  float m = -3.4e38f;
  #pragma unroll 4
  for (int r = 0; r < 128; ++r) m = fmaxf(m, -p[(size_t)r * N]);
  atomicMax(&colmax[j], fmap(m));
}

// Pass B: compact per-column candidates x > M_j - 1 (tau* >= M-1 always)
__global__ __launch_bounds__(256) void k_colcand(const float* __restrict__ cost,
      const unsigned* __restrict__ colmax, int* __restrict__ cnt,
      float* __restrict__ candv, int* __restrict__ candi){
  int j  = blockIdx.x * 256 + threadIdx.x;
  int r0 = blockIdx.y * 128;
  float th = funmap(colmax[j]) - 1.0f;
  const float* p = cost + (size_t)r0 * N + j;
  for (int r = 0; r < 128; ++r){
    float x = -p[(size_t)r * N];
    if (x > th){
      int q = atomicAdd(&cnt[j], 1);
      if (q < CAP){ candv[(size_t)j*CAP + q] = x; candi[(size_t)j*CAP + q] = r0 + r; }
    }
  }
}

// Row sparsemax: one block per row. Register-resident row, candidate + Michelot,
// writes row_alignment and sparse-accumulates beta[i,:] = sum_j p_ij * colvecs[j,:]
__global__ __launch_bounds__(256) void k_row(const float* __restrict__ cost,
      const float* __restrict__ colvecs, float* __restrict__ out_row,
      float* __restrict__ beta){
  const int i = blockIdx.x, t = threadIdx.x;
  const int w = t >> 6, lane = t & 63;
  __shared__ float s_red[4];
  __shared__ float s_M, s_tau, s_b;
  __shared__ int   s_cnt, s_cnt2;
  __shared__ float s_cv[CAP];
  __shared__ int   s_cj[CAP];

  const float4* row4 = (const float4*)(cost + (size_t)i * N);
  float4 x4[4];
  #pragma unroll
  for (int q = 0; q < 4; ++q){
    float4 v = row4[t + q * 256];
    x4[q] = make_float4(-v.x, -v.y, -v.z, -v.w);
  }
  float m = -3.4e38f;
  #pragma unroll
  for (int q = 0; q < 4; ++q)
    m = fmaxf(m, fmaxf(fmaxf(x4[q].x, x4[q].y), fmaxf(x4[q].z, x4[q].w)));
  for (int off = 32; off; off >>= 1) m = fmaxf(m, __shfl_xor(m, off));
  if (lane == 0) s_red[w] = m;
  if (t == 0){ s_cnt = 0; s_cnt2 = 0; }
  __syncthreads();
  if (t == 0) s_M = fmaxf(fmaxf(s_red[0], s_red[1]), fmaxf(s_red[2], s_red[3]));
  __syncthreads();
  const float M = s_M, th = M - 1.0f;

  #pragma unroll
  for (int q = 0; q < 4; ++q){
    const float* e = &x4[q].x;
    #pragma unroll
    for (int c = 0; c < 4; ++c){
      float v = e[c];
      if (v > th){ int p = atomicAdd(&s_cnt, 1); if (p < CAP) s_cv[p] = v; }
    }
  }
  __syncthreads();
  int c = s_cnt;
  if (c <= CAP){
    if (w == 0){
      float v[4];
      #pragma unroll
      for (int s = 0; s < 4; ++s){ int l = s * 64 + lane; v[s] = (l < c) ? s_cv[l] : -3.4e38f; }
      float tau = -3.0e38f;
      for (int it = 0; it < 48; ++it){
        float sum = 0.0f, cf = 0.0f;
        #pragma unroll
        for (int s = 0; s < 4; ++s) if (v[s] > tau){ sum += v[s]; cf += 1.0f; }
        for (int off = 32; off; off >>= 1){ sum += __shfl_xor(sum, off); cf += __shfl_xor(cf, off); }
        float nt = (sum - 1.0f) / cf;
        if (nt == tau) break;
        tau = nt;
      }
      if (lane == 0) s_tau = tau;
    }
    __syncthreads();
  } else {
    // fallback: block bisection on [M-1, M] (never taken for Gaussian input)
    float lo = th, hi = M;
    for (int it = 0; it < 40; ++it){
      float mid = 0.5f * (lo + hi);
      float part = 0.0f;
      #pragma unroll
      for (int q = 0; q < 4; ++q){
        const float* e = &x4[q].x;
        #pragma unroll
        for (int cc = 0; cc < 4; ++cc) part += fmaxf(e[cc] - mid, 0.0f);
      }
      for (int off = 32; off; off >>= 1) part += __shfl_xor(part, off);
      if (lane == 0) s_red[w] = part;
      __syncthreads();
      if (t == 0) s_b = s_red[0] + s_red[1] + s_red[2] + s_red[3];
      __syncthreads();
      if (s_b >= 1.0f) lo = mid; else hi = mid;
      __syncthreads();
    }
    if (t == 0) s_tau = lo;
    __syncthreads();
  }
  const float tau = s_tau;

  // write p (coalesced float4) + collect support pairs (reuse s_cv/s_cj)
  float4* orow4 = (float4*)(out_row + (size_t)i * N);
  #pragma unroll
  for (int q = 0; q < 4; ++q){
    float4 p;
    p.x = fmaxf(x4[q].x - tau, 0.0f);
    p.y = fmaxf(x4[q].y - tau, 0.0f);
    p.z = fmaxf(x4[q].z - tau, 0.0f);
    p.w = fmaxf(x4[q].w - tau, 0.0f);
    orow4[t + q * 256] = p;
    int jb = 4 * (t + q * 256);
    const float* e = &p.x;
    #pragma unroll
    for (int cc = 0; cc < 4; ++cc){
      if (e[cc] > 0.0f){
        int l = atomicAdd(&s_cnt2, 1);
        if (l < CAP){ s_cv[l] = e[cc]; s_cj[l] = jb + cc; }
      }
    }
  }
  __syncthreads();
  int ns = min(s_cnt2, CAP);
  float acc = 0.0f;
  for (int l = 0; l < ns; ++l)
    acc += s_cv[l] * colvecs[(size_t)s_cj[l] * DD + t];
  beta[(size_t)i * DD + t] = acc;
}

// Column tau (Michelot on candidates, one wave per column) + alpha[j,:] accumulation
__global__ __launch_bounds__(256) void k_coltau(const int* __restrict__ cnt,
      const float* __restrict__ candv, const int* __restrict__ candi,
      const float* __restrict__ rowvecs, float* __restrict__ tau_out,
      float* __restrict__ alpha){
  int t = threadIdx.x, w = t >> 6, lane = t & 63;
  int j = blockIdx.x * 4 + w;
  int c = min(cnt[j], CAP);
  const float* cv = candv + (size_t)j * CAP;
  const int*   ci = candi + (size_t)j * CAP;
  float v[4];
  #pragma unroll
  for (int s = 0; s < 4; ++s){ int l = s * 64 + lane; v[s] = (l < c) ? cv[l] : -3.4e38f; }
  float tau = -3.0e38f;
  for (int it = 0; it < 48; ++it){
    float sum = 0.0f, cf = 0.0f;
    #pragma unroll
    for (int s = 0; s < 4; ++s) if (v[s] > tau){ sum += v[s]; cf += 1.0f; }
    for (int off = 32; off; off >>= 1){ sum += __shfl_xor(sum, off); cf += __shfl_xor(cf, off); }
    float nt = (sum - 1.0f) / cf;
    if (nt == tau) break;
    tau = nt;
  }
  if (lane == 0) tau_out[j] = tau;

  float a0 = 0, a1 = 0, a2 = 0, a3 = 0;
  for (int l = 0; l < c; ++l){
    float p = cv[l] - tau;
    if (p > 0.0f){
      const float* ar = rowvecs + (size_t)ci[l] * DD;
      a0 += p * ar[lane];        a1 += p * ar[64 + lane];
      a2 += p * ar[128 + lane];  a3 += p * ar[192 + lane];
    }
  }
  float* al = alpha + (size_t)j * DD;
  al[lane] = a0; al[64 + lane] = a1; al[128 + lane] = a2; al[192 + lane] = a3;
}

// G(x) = leaky_relu(x @ W + b); accumulate column sums for the means
__global__ __launch_bounds__(256) void k_G(const float* __restrict__ beta,
      const float* __restrict__ alpha, const float* __restrict__ W,
      const float* __restrict__ bG, float* __restrict__ vsum){
  int t = threadIdx.x, side = blockIdx.y, r0 = blockIdx.x * 16;
  const float* src = side ? alpha : beta;
  __shared__ float sB[16 * 256];
  #pragma unroll
  for (int k = 0; k < 16; ++k) sB[k * 256 + t] = src[(size_t)(r0 + k) * 256 + t];
  __syncthreads();
  float acc[16];
  float bg = bG[t];
  #pragma unroll
  for (int r = 0; r < 16; ++r) acc[r] = bg;
  const float4* sB4 = (const float4*)sB;
  for (int d4 = 0; d4 < 64; ++d4){
    int d = d4 * 4;
    float w0 = W[(size_t)d * 256 + t];
    float w1 = W[(size_t)(d + 1) * 256 + t];
    float w2 = W[(size_t)(d + 2) * 256 + t];
    float w3 = W[(size_t)(d + 3) * 256 + t];
    #pragma unroll
    for (int r = 0; r < 16; ++r){
      float4 s = sB4[r * 64 + d4];
      acc[r] += s.x * w0 + s.y * w1 + s.z * w2 + s.w * w3;
    }
  }
  float s = 0.0f;
  #pragma unroll
  for (int r = 0; r < 16; ++r){ float u = acc[r]; s += (u > 0.0f) ? u : LEAKY * u; }
  atomicAdd(&vsum[side * 256 + t], s);
}

// cosine cost scalar
__global__ __launch_bounds__(256) void k_final(const float* __restrict__ vsum,
                                               float* __restrict__ y){
  int t = threadIdx.x, w = t >> 6, lane = t & 63;
  __shared__ float rd[3][4];
  float v1 = vsum[t]       * (1.0f / 4096.0f);
  float v2 = vsum[256 + t] * (1.0f / 4096.0f);
  float d = v1 * v2, a = v1 * v1, b = v2 * v2;
  for (int off = 32; off; off >>= 1){
    d += __shfl_xor(d, off); a += __shfl_xor(a, off); b += __shfl_xor(b, off);
  }
  if (lane == 0){ rd[0][w] = d; rd[1][w] = a; rd[2][w] = b; }
  __syncthreads();
  if (t == 0){
    float dd = rd[0][0] + rd[0][1] + rd[0][2] + rd[0][3];
    float aa = rd[1][0] + rd[1][1] + rd[1][2] + rd[1][3];
    float bb = rd[2][0] + rd[2][1] + rd[2][2] + rd[2][3];
    y[0] = 1.0f - dd / (sqrtf(aa) * sqrtf(bb) + 1e-8f);
  }
}

// final pass: column alignment in natural [i][j] layout + y-broadcast fill (fused,
// reuses the single read of cost)
__global__ __launch_bounds__(256) void k_finish(const float* __restrict__ cost,
      const float* __restrict__ tau, const float* __restrict__ ypt,
      float* __restrict__ out0, float* __restrict__ outcol){
  int idx = blockIdx.x * 256 + threadIdx.x;          // float4 index
  float4 cc = ((const float4*)cost)[idx];
  float4 tt = ((const float4*)tau)[idx & 1023];
  float  y  = ypt[0];
  float4 p;
  p.x = fmaxf(-cc.x - tt.x, 0.0f);
  p.y = fmaxf(-cc.y - tt.y, 0.0f);
  p.z = fmaxf(-cc.z - tt.z, 0.0f);
  p.w = fmaxf(-cc.w - tt.w, 0.0f);
  ((float4*)outcol)[idx] = p;
  ((float4*)out0)[idx]   = make_float4(y, y, y, y);
}

extern "C" void kernel_launch(void* const* d_in, const int* in_sizes, int n_in,
                              void* d_out, int out_size, void* d_ws, size_t ws_size,
                              hipStream_t stream){
  const float* rowv = (const float*)d_in[0];   // [4096,256]
  const float* colv = (const float*)d_in[1];   // [4096,256]
  const float* cost = (const float*)d_in[2];   // [4096,4096]
  const float* W    = (const float*)d_in[3];   // [256,256]
  const float* bG   = (const float*)d_in[4];   // [256]

  float* out0    = (float*)d_out;                       // cost_matrix
  float* out_row = out0 + (size_t)N * N;                // alignment[0]
  float* out_col = out0 + 2 * (size_t)N * N;            // alignment[1]

  // workspace layout (floats): colmax[4096] cnt[4096] vsum[512] tau[4096]
  //                            beta[1M] alpha[1M] candv[1M] candi[1M] y[1]  ~16.8 MB
  unsigned* colmax = (unsigned*)d_ws;
  int*      cnt    = (int*)d_ws + 4096;
  float*    vsum   = (float*)d_ws + 8192;
  float*    tau    = (float*)d_ws + 8704;
  float*    beta   = (float*)d_ws + 12800;
  float*    alpha  = (float*)d_ws + 12800 + 1 * 1048576;
  float*    candv  = (float*)d_ws + 12800 + 2 * 1048576;
  int*      candi  = (int*)d_ws   + 12800 + 3 * 1048576;
  float*    ypt    = (float*)d_ws + 12800 + 4 * 1048576;

  // zero colmax + cnt + vsum (contiguous prefix)
  hipMemsetAsync(d_ws, 0, (size_t)(8192 + 512) * 4, stream);

  dim3 slab(16, 32);
  hipLaunchKernelGGL(k_colmax,  slab,        dim3(256), 0, stream, cost, colmax);
  hipLaunchKernelGGL(k_colcand, slab,        dim3(256), 0, stream, cost, colmax, cnt, candv, candi);
  hipLaunchKernelGGL(k_row,     dim3(4096),  dim3(256), 0, stream, cost, colv, out_row, beta);
  hipLaunchKernelGGL(k_coltau,  dim3(1024),  dim3(256), 0, stream, cnt, candv, candi, rowv, tau, alpha);
  hipLaunchKernelGGL(k_G,       dim3(256,2), dim3(256), 0, stream, beta, alpha, W, bG, vsum);
  hipLaunchKernelGGL(k_final,   dim3(1),     dim3(256), 0, stream, vsum, ypt);
  hipLaunchKernelGGL(k_finish,  dim3(16384), dim3(256), 0, stream, cost, tau, ypt, out0, out_col);
}

// Round 2
// 412.708 us; speedup vs baseline: 1.0639x; 1.0639x over previous
//
#include <hip/hip_runtime.h>
#include <math.h>

#define N 4096
#define DD 256
#define CAP 512      // per-column candidate capacity (slab-local thresholds -> ~120 typical)
#define RCAP 256     // per-row support capacity
#define LEAKY 0.2f

// ---------------------------------------------------------------------------
// Pass 1: single-read column candidate compaction.
// Block = 256 thr covers 64 columns x 512 rows. Each thread holds 128 values
// of one column in registers, 4 threads/column merge their maxes via LDS.
// Threshold m512-1 is a conservative superset of the true support since
// tau*_j >= M_j - 1 >= m_slab - 1  (Michelot on a superset is exact).
// ---------------------------------------------------------------------------
__global__ __launch_bounds__(256, 2) void k_colcand2(const float* __restrict__ cost,
      int* __restrict__ cnt, float* __restrict__ candv, int* __restrict__ candi){
  const int tc = threadIdx.x & 63;        // column within group
  const int tr = threadIdx.x >> 6;        // row sub-chunk 0..3
  const int j  = blockIdx.x * 64 + tc;
  const int r0 = blockIdx.y * 512 + tr * 128;
  const float* p = cost + (size_t)r0 * N + j;

  float v[128];
  #pragma unroll
  for (int r = 0; r < 128; ++r) v[r] = -p[(size_t)r * N];

  float m = v[0];
  #pragma unroll
  for (int r = 1; r < 128; ++r) m = fmaxf(m, v[r]);

  __shared__ float smax[4][64];
  smax[tr][tc] = m;
  __syncthreads();
  const float m4 = fmaxf(fmaxf(smax[0][tc], smax[1][tc]),
                         fmaxf(smax[2][tc], smax[3][tc]));
  const float th = m4 - 1.0f;

  #pragma unroll
  for (int r = 0; r < 128; ++r){
    if (v[r] > th){
      int q = atomicAdd(&cnt[j], 1);
      if (q < CAP){ candv[(size_t)j * CAP + q] = v[r]; candi[(size_t)j * CAP + q] = r0 + r; }
    }
  }
}

// ---------------------------------------------------------------------------
// Column tau (Michelot on candidates, one wave per column) + alpha[j,:]
// ---------------------------------------------------------------------------
__global__ __launch_bounds__(256) void k_coltau(const int* __restrict__ cnt,
      const float* __restrict__ candv, const int* __restrict__ candi,
      const float* __restrict__ rowvecs, float* __restrict__ tau_out,
      float* __restrict__ alpha){
  const int t = threadIdx.x, w = t >> 6, lane = t & 63;
  const int j = blockIdx.x * 4 + w;
  const int c = min(cnt[j], CAP);
  const float* cv = candv + (size_t)j * CAP;
  const int*   ci = candi + (size_t)j * CAP;

  float v[8];
  #pragma unroll
  for (int s = 0; s < 8; ++s){ int l = s * 64 + lane; v[s] = (l < c) ? cv[l] : -3.4e38f; }

  float tau = -3.0e38f;
  for (int it = 0; it < 48; ++it){
    float sum = 0.0f, cf = 0.0f;
    #pragma unroll
    for (int s = 0; s < 8; ++s) if (v[s] > tau){ sum += v[s]; cf += 1.0f; }
    for (int off = 32; off; off >>= 1){ sum += __shfl_xor(sum, off); cf += __shfl_xor(cf, off); }
    float nt = (sum - 1.0f) / cf;
    if (nt == tau) break;
    tau = nt;
  }
  if (lane == 0) tau_out[j] = tau;

  float a0 = 0, a1 = 0, a2 = 0, a3 = 0;
  for (int l = 0; l < c; ++l){
    float pp = cv[l] - tau;
    if (pp > 0.0f){
      const float* ar = rowvecs + (size_t)ci[l] * DD;
      a0 += pp * ar[lane];        a1 += pp * ar[64 + lane];
      a2 += pp * ar[128 + lane];  a3 += pp * ar[192 + lane];
    }
  }
  float* al = alpha + (size_t)j * DD;
  al[lane] = a0; al[64 + lane] = a1; al[128 + lane] = a2; al[192 + lane] = a3;
}

// ---------------------------------------------------------------------------
// Row sparsemax, FUSED: reads cost row once; writes row_alignment AND
// column_alignment (tau_col available); accumulates beta[i,:].
// ---------------------------------------------------------------------------
__global__ __launch_bounds__(256) void k_row(const float* __restrict__ cost,
      const float* __restrict__ colvecs, const float* __restrict__ tau_col,
      float* __restrict__ out_row, float* __restrict__ out_col,
      float* __restrict__ beta){
  const int i = blockIdx.x, t = threadIdx.x;
  const int w = t >> 6, lane = t & 63;
  __shared__ float s_red[4];
  __shared__ float s_M, s_tau, s_b;
  __shared__ int   s_cnt, s_cnt2;
  __shared__ float s_cv[RCAP];
  __shared__ int   s_cj[RCAP];

  const float4* row4 = (const float4*)(cost + (size_t)i * N);
  float4 x4[4];
  #pragma unroll
  for (int q = 0; q < 4; ++q){
    float4 v = row4[t + q * 256];
    x4[q] = make_float4(-v.x, -v.y, -v.z, -v.w);
  }
  float m = -3.4e38f;
  #pragma unroll
  for (int q = 0; q < 4; ++q)
    m = fmaxf(m, fmaxf(fmaxf(x4[q].x, x4[q].y), fmaxf(x4[q].z, x4[q].w)));
  for (int off = 32; off; off >>= 1) m = fmaxf(m, __shfl_xor(m, off));
  if (lane == 0) s_red[w] = m;
  if (t == 0){ s_cnt = 0; s_cnt2 = 0; }
  __syncthreads();
  if (t == 0) s_M = fmaxf(fmaxf(s_red[0], s_red[1]), fmaxf(s_red[2], s_red[3]));
  __syncthreads();
  const float M = s_M, th = M - 1.0f;

  #pragma unroll
  for (int q = 0; q < 4; ++q){
    const float* e = &x4[q].x;
    #pragma unroll
    for (int c = 0; c < 4; ++c){
      float v = e[c];
      if (v > th){ int p = atomicAdd(&s_cnt, 1); if (p < RCAP) s_cv[p] = v; }
    }
  }
  __syncthreads();
  int c = s_cnt;
  if (c <= RCAP){
    if (w == 0){
      float v[4];
      #pragma unroll
      for (int s = 0; s < 4; ++s){ int l = s * 64 + lane; v[s] = (l < c) ? s_cv[l] : -3.4e38f; }
      float tau = -3.0e38f;
      for (int it = 0; it < 48; ++it){
        float sum = 0.0f, cf = 0.0f;
        #pragma unroll
        for (int s = 0; s < 4; ++s) if (v[s] > tau){ sum += v[s]; cf += 1.0f; }
        for (int off = 32; off; off >>= 1){ sum += __shfl_xor(sum, off); cf += __shfl_xor(cf, off); }
        float nt = (sum - 1.0f) / cf;
        if (nt == tau) break;
        tau = nt;
      }
      if (lane == 0) s_tau = tau;
    }
    __syncthreads();
  } else {
    // fallback: block bisection on [M-1, M] (not taken for this input)
    float lo = th, hi = M;
    for (int it = 0; it < 40; ++it){
      float mid = 0.5f * (lo + hi);
      float part = 0.0f;
      #pragma unroll
      for (int q = 0; q < 4; ++q){
        const float* e = &x4[q].x;
        #pragma unroll
        for (int cc = 0; cc < 4; ++cc) part += fmaxf(e[cc] - mid, 0.0f);
      }
      for (int off = 32; off; off >>= 1) part += __shfl_xor(part, off);
      if (lane == 0) s_red[w] = part;
      __syncthreads();
      if (t == 0) s_b = s_red[0] + s_red[1] + s_red[2] + s_red[3];
      __syncthreads();
      if (s_b >= 1.0f) lo = mid; else hi = mid;
      __syncthreads();
    }
    if (t == 0) s_tau = lo;
    __syncthreads();
  }
  const float tau = s_tau;

  // write row alignment + column alignment (fused; cost read only once)
  const float4* tau4 = (const float4*)tau_col;
  float4* orow4 = (float4*)(out_row + (size_t)i * N);
  float4* ocol4 = (float4*)(out_col + (size_t)i * N);
  #pragma unroll
  for (int q = 0; q < 4; ++q){
    float4 p;
    p.x = fmaxf(x4[q].x - tau, 0.0f);
    p.y = fmaxf(x4[q].y - tau, 0.0f);
    p.z = fmaxf(x4[q].z - tau, 0.0f);
    p.w = fmaxf(x4[q].w - tau, 0.0f);
    orow4[t + q * 256] = p;

    float4 tt = tau4[t + q * 256];
    float4 pc;
    pc.x = fmaxf(x4[q].x - tt.x, 0.0f);
    pc.y = fmaxf(x4[q].y - tt.y, 0.0f);
    pc.z = fmaxf(x4[q].z - tt.z, 0.0f);
    pc.w = fmaxf(x4[q].w - tt.w, 0.0f);
    ocol4[t + q * 256] = pc;

    int jb = 4 * (t + q * 256);
    const float* e = &p.x;
    #pragma unroll
    for (int cc = 0; cc < 4; ++cc){
      if (e[cc] > 0.0f){
        int l = atomicAdd(&s_cnt2, 1);
        if (l < RCAP){ s_cv[l] = e[cc]; s_cj[l] = jb + cc; }
      }
    }
  }
  __syncthreads();
  int ns = min(s_cnt2, RCAP);
  float acc = 0.0f;
  for (int l = 0; l < ns; ++l)
    acc += s_cv[l] * colvecs[(size_t)s_cj[l] * DD + t];
  beta[(size_t)i * DD + t] = acc;
}

// ---------------------------------------------------------------------------
// G(x) = leaky_relu(x @ W + b); accumulate column sums for the means
// ---------------------------------------------------------------------------
__global__ __launch_bounds__(256) void k_G(const float* __restrict__ beta,
      const float* __restrict__ alpha, const float* __restrict__ W,
      const float* __restrict__ bG, float* __restrict__ vsum){
  int t = threadIdx.x, side = blockIdx.y, r0 = blockIdx.x * 16;
  const float* src = side ? alpha : beta;
  __shared__ float sB[16 * 256];
  #pragma unroll
  for (int k = 0; k < 16; ++k) sB[k * 256 + t] = src[(size_t)(r0 + k) * 256 + t];
  __syncthreads();
  float acc[16];
  float bg = bG[t];
  #pragma unroll
  for (int r = 0; r < 16; ++r) acc[r] = bg;
  const float4* sB4 = (const float4*)sB;
  for (int d4 = 0; d4 < 64; ++d4){
    int d = d4 * 4;
    float w0 = W[(size_t)d * 256 + t];
    float w1 = W[(size_t)(d + 1) * 256 + t];
    float w2 = W[(size_t)(d + 2) * 256 + t];
    float w3 = W[(size_t)(d + 3) * 256 + t];
    #pragma unroll
    for (int r = 0; r < 16; ++r){
      float4 s = sB4[r * 64 + d4];
      acc[r] += s.x * w0 + s.y * w1 + s.z * w2 + s.w * w3;
    }
  }
  float s = 0.0f;
  #pragma unroll
  for (int r = 0; r < 16; ++r){ float u = acc[r]; s += (u > 0.0f) ? u : LEAKY * u; }
  atomicAdd(&vsum[side * 256 + t], s);
}

// cosine cost scalar
__global__ __launch_bounds__(256) void k_final(const float* __restrict__ vsum,
                                               float* __restrict__ y){
  int t = threadIdx.x, w = t >> 6, lane = t & 63;
  __shared__ float rd[3][4];
  float v1 = vsum[t]       * (1.0f / 4096.0f);
  float v2 = vsum[256 + t] * (1.0f / 4096.0f);
  float d = v1 * v2, a = v1 * v1, b = v2 * v2;
  for (int off = 32; off; off >>= 1){
    d += __shfl_xor(d, off); a += __shfl_xor(a, off); b += __shfl_xor(b, off);
  }
  if (lane == 0){ rd[0][w] = d; rd[1][w] = a; rd[2][w] = b; }
  __syncthreads();
  if (t == 0){
    float dd = rd[0][0] + rd[0][1] + rd[0][2] + rd[0][3];
    float aa = rd[1][0] + rd[1][1] + rd[1][2] + rd[1][3];
    float bb = rd[2][0] + rd[2][1] + rd[2][2] + rd[2][3];
    y[0] = 1.0f - dd / (sqrtf(aa) * sqrtf(bb) + 1e-8f);
  }
}

// write-only broadcast of y into out0
__global__ __launch_bounds__(256) void k_fill(const float* __restrict__ ypt,
                                              float4* __restrict__ out0){
  int idx = blockIdx.x * 256 + threadIdx.x;
  float y = ypt[0];
  out0[idx] = make_float4(y, y, y, y);
}

extern "C" void kernel_launch(void* const* d_in, const int* in_sizes, int n_in,
                              void* d_out, int out_size, void* d_ws, size_t ws_size,
                              hipStream_t stream){
  const float* rowv = (const float*)d_in[0];   // [4096,256]
  const float* colv = (const float*)d_in[1];   // [4096,256]
  const float* cost = (const float*)d_in[2];   // [4096,4096]
  const float* W    = (const float*)d_in[3];   // [256,256]
  const float* bG   = (const float*)d_in[4];   // [256]

  float* out0    = (float*)d_out;                       // cost_matrix
  float* out_row = out0 + (size_t)N * N;                // alignment[0]
  float* out_col = out0 + 2 * (size_t)N * N;            // alignment[1]

  // ws layout (float units): cnt[4096] vsum[512] tau[4096] beta[1M] alpha[1M]
  //                          candv[2M] candi[2M] y[1]   (~25.2 MB)
  int*   cnt   = (int*)d_ws;
  float* vsum  = (float*)d_ws + 4096;
  float* tau   = (float*)d_ws + 4608;
  float* beta  = (float*)d_ws + 8704;
  float* alpha = (float*)d_ws + 8704 + 1048576;
  float* candv = (float*)d_ws + 8704 + 2 * 1048576;
  int*   candi = (int*)d_ws   + 8704 + 4 * 1048576;     // candv is CAP*4096 = 2M floats
  float* ypt   = (float*)d_ws + 8704 + 6 * 1048576;

  // zero cnt + vsum (contiguous prefix)
  hipMemsetAsync(d_ws, 0, (size_t)4608 * 4, stream);

  hipLaunchKernelGGL(k_colcand2, dim3(64, 8), dim3(256), 0, stream, cost, cnt, candv, candi);
  hipLaunchKernelGGL(k_coltau,   dim3(1024),  dim3(256), 0, stream, cnt, candv, candi, rowv, tau, alpha);
  hipLaunchKernelGGL(k_row,      dim3(4096),  dim3(256), 0, stream, cost, colv, tau, out_row, out_col, beta);
  hipLaunchKernelGGL(k_G,        dim3(256,2), dim3(256), 0, stream, beta, alpha, W, bG, vsum);
  hipLaunchKernelGGL(k_final,    dim3(1),     dim3(256), 0, stream, vsum, ypt);
  hipLaunchKernelGGL(k_fill,     dim3(16384), dim3(256), 0, stream, ypt, (float4*)out0);
}

// Round 3
// 393.879 us; speedup vs baseline: 1.1148x; 1.0478x over previous
//
#include <hip/hip_runtime.h>
#include <math.h>

#define N 4096
#define DD 256
#define CAP 512      // per-column candidate capacity
#define RCAP 256     // per-row support capacity
#define LEAKY 0.2f

// ---------------------------------------------------------------------------
// Pass 1: single-read column candidate compaction.
// Block = 256 thr covers 64 columns x 512 rows; thread holds 128 values of one
// column in registers; 4 threads/column merge maxes via LDS. Threshold
// m_slab-1 <= M_j-1 <= tau*_j, so the compacted set is a conservative superset
// of the support (Michelot on a superset is exact).
// Candidates are buffered per-thread and flushed with ONE atomic reserve.
// ---------------------------------------------------------------------------
__global__ __launch_bounds__(256, 2) void k_colcand2(const float* __restrict__ cost,
      int* __restrict__ cnt, float* __restrict__ candv, int* __restrict__ candi){
  const int tc = threadIdx.x & 63;
  const int tr = threadIdx.x >> 6;
  const int j  = blockIdx.x * 64 + tc;
  const int r0 = blockIdx.y * 512 + tr * 128;
  const float* p = cost + (size_t)r0 * N + j;

  float v[128];
  #pragma unroll
  for (int r = 0; r < 128; ++r) v[r] = -p[(size_t)r * N];

  float m = v[0];
  #pragma unroll
  for (int r = 1; r < 128; ++r) m = fmaxf(m, v[r]);

  __shared__ float smax[4][64];
  smax[tr][tc] = m;
  __syncthreads();
  const float m4 = fmaxf(fmaxf(smax[0][tc], smax[1][tc]),
                         fmaxf(smax[2][tc], smax[3][tc]));
  const float th = m4 - 1.0f;

  // local buffer, single atomic reserve per flush
  float lv[16]; int li[16]; int nl = 0;
  #pragma unroll
  for (int r = 0; r < 128; ++r){
    if (v[r] > th){
      lv[nl] = v[r]; li[nl] = r0 + r; ++nl;
      if (nl == 16){
        int q0 = atomicAdd(&cnt[j], 16);
        #pragma unroll
        for (int k = 0; k < 16; ++k){
          int q = q0 + k;
          if (q < CAP){ candv[(size_t)j * CAP + q] = lv[k]; candi[(size_t)j * CAP + q] = li[k]; }
        }
        nl = 0;
      }
    }
  }
  if (nl > 0){
    int q0 = atomicAdd(&cnt[j], nl);
    for (int k = 0; k < nl; ++k){
      int q = q0 + k;
      if (q < CAP){ candv[(size_t)j * CAP + q] = lv[k]; candi[(size_t)j * CAP + q] = li[k]; }
    }
  }
}

// ---------------------------------------------------------------------------
// Column tau (Michelot on candidates, one wave per column) + alpha[j,:].
// Candidates preloaded into registers (pipelined loads); support compacted
// into LDS via ballot-prefix; gather loop has independent iterations (MLP).
// ---------------------------------------------------------------------------
__global__ __launch_bounds__(256) void k_coltau(const int* __restrict__ cnt,
      const float* __restrict__ candv, const int* __restrict__ candi,
      const float* __restrict__ rowvecs, float* __restrict__ tau_out,
      float* __restrict__ alpha){
  const int t = threadIdx.x, w = t >> 6, lane = t & 63;
  const int j = blockIdx.x * 4 + w;
  const int c = min(cnt[j], CAP);
  const float* cv = candv + (size_t)j * CAP;
  const int*   ci = candi + (size_t)j * CAP;

  float v[8]; int id[8];
  #pragma unroll
  for (int s = 0; s < 8; ++s){
    int l = s * 64 + lane;
    v[s]  = (l < c) ? cv[l] : -3.4e38f;
    id[s] = (l < c) ? ci[l] : 0;
  }

  float tau = -3.0e38f;
  for (int it = 0; it < 40; ++it){
    float sum = 0.0f, cf = 0.0f;
    #pragma unroll
    for (int s = 0; s < 8; ++s) if (v[s] > tau){ sum += v[s]; cf += 1.0f; }
    for (int off = 32; off; off >>= 1){ sum += __shfl_xor(sum, off); cf += __shfl_xor(cf, off); }
    float nt = (sum - 1.0f) / cf;
    if (nt == tau) break;
    tau = nt;
  }
  if (lane == 0) tau_out[j] = tau;

  // compact support (p = v - tau > 0) into per-wave LDS
  __shared__ float sup_v[4][CAP];
  __shared__ int   sup_i[4][CAP];
  const unsigned long long lmask = (lane == 63) ? ~0ULL >> 1 : (1ULL << lane) - 1;
  int base = 0;
  #pragma unroll
  for (int s = 0; s < 8; ++s){
    bool pred = (v[s] > tau);
    unsigned long long mk = __ballot(pred);
    if (pred){
      int pos = base + __popcll(mk & ((1ULL << lane) - 1ULL));
      sup_v[w][pos] = v[s] - tau;
      sup_i[w][pos] = id[s];
    }
    base += __popcll(mk);
  }
  const int ns = base;
  __builtin_amdgcn_wave_barrier();   // LDS writes -> reads within same wave
  __asm__ volatile("s_waitcnt lgkmcnt(0)");

  float a0 = 0, a1 = 0, a2 = 0, a3 = 0;
  #pragma unroll 4
  for (int l = 0; l < ns; ++l){
    float pp = sup_v[w][l];
    const float* ar = rowvecs + (size_t)sup_i[w][l] * DD;
    a0 += pp * ar[lane];        a1 += pp * ar[64 + lane];
    a2 += pp * ar[128 + lane];  a3 += pp * ar[192 + lane];
  }
  float* al = alpha + (size_t)j * DD;
  al[lane] = a0; al[64 + lane] = a1; al[128 + lane] = a2; al[192 + lane] = a3;
}

// ---------------------------------------------------------------------------
// Row sparsemax, FUSED: reads cost row once; writes row_alignment AND
// column_alignment; accumulates beta[i,:].
// ---------------------------------------------------------------------------
__global__ __launch_bounds__(256) void k_row(const float* __restrict__ cost,
      const float* __restrict__ colvecs, const float* __restrict__ tau_col,
      float* __restrict__ out_row, float* __restrict__ out_col,
      float* __restrict__ beta){
  const int i = blockIdx.x, t = threadIdx.x;
  const int w = t >> 6, lane = t & 63;
  __shared__ float s_red[4];
  __shared__ float s_M, s_tau, s_b;
  __shared__ int   s_cnt, s_cnt2;
  __shared__ float s_cv[RCAP];
  __shared__ int   s_cj[RCAP];

  const float4* row4 = (const float4*)(cost + (size_t)i * N);
  const float4* tau4 = (const float4*)tau_col;
  float4 x4[4], tt4[4];
  #pragma unroll
  for (int q = 0; q < 4; ++q){
    float4 v = row4[t + q * 256];
    x4[q] = make_float4(-v.x, -v.y, -v.z, -v.w);
    tt4[q] = tau4[t + q * 256];     // hoisted: overlaps reductions/Michelot
  }
  float m = -3.4e38f;
  #pragma unroll
  for (int q = 0; q < 4; ++q)
    m = fmaxf(m, fmaxf(fmaxf(x4[q].x, x4[q].y), fmaxf(x4[q].z, x4[q].w)));
  for (int off = 32; off; off >>= 1) m = fmaxf(m, __shfl_xor(m, off));
  if (lane == 0) s_red[w] = m;
  if (t == 0){ s_cnt = 0; s_cnt2 = 0; }
  __syncthreads();
  if (t == 0) s_M = fmaxf(fmaxf(s_red[0], s_red[1]), fmaxf(s_red[2], s_red[3]));
  __syncthreads();
  const float M = s_M, th = M - 1.0f;

  #pragma unroll
  for (int q = 0; q < 4; ++q){
    const float* e = &x4[q].x;
    #pragma unroll
    for (int c = 0; c < 4; ++c){
      float v = e[c];
      if (v > th){ int p = atomicAdd(&s_cnt, 1); if (p < RCAP) s_cv[p] = v; }
    }
  }
  __syncthreads();
  int c = s_cnt;
  if (c <= RCAP){
    if (w == 0){
      float v[4];
      #pragma unroll
      for (int s = 0; s < 4; ++s){ int l = s * 64 + lane; v[s] = (l < c) ? s_cv[l] : -3.4e38f; }
      float tau = -3.0e38f;
      for (int it = 0; it < 40; ++it){
        float sum = 0.0f, cf = 0.0f;
        #pragma unroll
        for (int s = 0; s < 4; ++s) if (v[s] > tau){ sum += v[s]; cf += 1.0f; }
        for (int off = 32; off; off >>= 1){ sum += __shfl_xor(sum, off); cf += __shfl_xor(cf, off); }
        float nt = (sum - 1.0f) / cf;
        if (nt == tau) break;
        tau = nt;
      }
      if (lane == 0) s_tau = tau;
    }
    __syncthreads();
  } else {
    // fallback: block bisection on [M-1, M] (not taken for this input)
    float lo = th, hi = M;
    for (int it = 0; it < 40; ++it){
      float mid = 0.5f * (lo + hi);
      float part = 0.0f;
      #pragma unroll
      for (int q = 0; q < 4; ++q){
        const float* e = &x4[q].x;
        #pragma unroll
        for (int cc = 0; cc < 4; ++cc) part += fmaxf(e[cc] - mid, 0.0f);
      }
      for (int off = 32; off; off >>= 1) part += __shfl_xor(part, off);
      if (lane == 0) s_red[w] = part;
      __syncthreads();
      if (t == 0) s_b = s_red[0] + s_red[1] + s_red[2] + s_red[3];
      __syncthreads();
      if (s_b >= 1.0f) lo = mid; else hi = mid;
      __syncthreads();
    }
    if (t == 0) s_tau = lo;
    __syncthreads();
  }
  const float tau = s_tau;

  // write row alignment + column alignment (cost read only once)
  float4* orow4 = (float4*)(out_row + (size_t)i * N);
  float4* ocol4 = (float4*)(out_col + (size_t)i * N);
  #pragma unroll
  for (int q = 0; q < 4; ++q){
    float4 p;
    p.x = fmaxf(x4[q].x - tau, 0.0f);
    p.y = fmaxf(x4[q].y - tau, 0.0f);
    p.z = fmaxf(x4[q].z - tau, 0.0f);
    p.w = fmaxf(x4[q].w - tau, 0.0f);
    orow4[t + q * 256] = p;

    float4 pc;
    pc.x = fmaxf(x4[q].x - tt4[q].x, 0.0f);
    pc.y = fmaxf(x4[q].y - tt4[q].y, 0.0f);
    pc.z = fmaxf(x4[q].z - tt4[q].z, 0.0f);
    pc.w = fmaxf(x4[q].w - tt4[q].w, 0.0f);
    ocol4[t + q * 256] = pc;

    int jb = 4 * (t + q * 256);
    const float* e = &p.x;
    #pragma unroll
    for (int cc = 0; cc < 4; ++cc){
      if (e[cc] > 0.0f){
        int l = atomicAdd(&s_cnt2, 1);
        if (l < RCAP){ s_cv[l] = e[cc]; s_cj[l] = jb + cc; }
      }
    }
  }
  __syncthreads();
  int ns = min(s_cnt2, RCAP);
  float acc = 0.0f;
  #pragma unroll 4
  for (int l = 0; l < ns; ++l)
    acc += s_cv[l] * colvecs[(size_t)s_cj[l] * DD + t];
  beta[(size_t)i * DD + t] = acc;
}

// ---------------------------------------------------------------------------
// G(x) = leaky_relu(x @ W + b); accumulate column sums for the means
// ---------------------------------------------------------------------------
__global__ __launch_bounds__(256) void k_G(const float* __restrict__ beta,
      const float* __restrict__ alpha, const float* __restrict__ W,
      const float* __restrict__ bG, float* __restrict__ vsum){
  int t = threadIdx.x, side = blockIdx.y, r0 = blockIdx.x * 16;
  const float* src = side ? alpha : beta;
  __shared__ float sB[16 * 256];
  #pragma unroll
  for (int k = 0; k < 16; ++k) sB[k * 256 + t] = src[(size_t)(r0 + k) * 256 + t];
  __syncthreads();
  float acc[16];
  float bg = bG[t];
  #pragma unroll
  for (int r = 0; r < 16; ++r) acc[r] = bg;
  const float4* sB4 = (const float4*)sB;
  for (int d4 = 0; d4 < 64; ++d4){
    int d = d4 * 4;
    float w0 = W[(size_t)d * 256 + t];
    float w1 = W[(size_t)(d + 1) * 256 + t];
    float w2 = W[(size_t)(d + 2) * 256 + t];
    float w3 = W[(size_t)(d + 3) * 256 + t];
    #pragma unroll
    for (int r = 0; r < 16; ++r){
      float4 s = sB4[r * 64 + d4];
      acc[r] += s.x * w0 + s.y * w1 + s.z * w2 + s.w * w3;
    }
  }
  float s = 0.0f;
  #pragma unroll
  for (int r = 0; r < 16; ++r){ float u = acc[r]; s += (u > 0.0f) ? u : LEAKY * u; }
  atomicAdd(&vsum[side * 256 + t], s);
}

// cosine cost scalar
__global__ __launch_bounds__(256) void k_final(const float* __restrict__ vsum,
                                               float* __restrict__ y){
  int t = threadIdx.x, w = t >> 6, lane = t & 63;
  __shared__ float rd[3][4];
  float v1 = vsum[t]       * (1.0f / 4096.0f);
  float v2 = vsum[256 + t] * (1.0f / 4096.0f);
  float d = v1 * v2, a = v1 * v1, b = v2 * v2;
  for (int off = 32; off; off >>= 1){
    d += __shfl_xor(d, off); a += __shfl_xor(a, off); b += __shfl_xor(b, off);
  }
  if (lane == 0){ rd[0][w] = d; rd[1][w] = a; rd[2][w] = b; }
  __syncthreads();
  if (t == 0){
    float dd = rd[0][0] + rd[0][1] + rd[0][2] + rd[0][3];
    float aa = rd[1][0] + rd[1][1] + rd[1][2] + rd[1][3];
    float bb = rd[2][0] + rd[2][1] + rd[2][2] + rd[2][3];
    y[0] = 1.0f - dd / (sqrtf(aa) * sqrtf(bb) + 1e-8f);
  }
}

// write-only broadcast of y into out0
__global__ __launch_bounds__(256) void k_fill(const float* __restrict__ ypt,
                                              float4* __restrict__ out0){
  int idx = blockIdx.x * 256 + threadIdx.x;
  float y = ypt[0];
  out0[idx] = make_float4(y, y, y, y);
}

extern "C" void kernel_launch(void* const* d_in, const int* in_sizes, int n_in,
                              void* d_out, int out_size, void* d_ws, size_t ws_size,
                              hipStream_t stream){
  const float* rowv = (const float*)d_in[0];   // [4096,256]
  const float* colv = (const float*)d_in[1];   // [4096,256]
  const float* cost = (const float*)d_in[2];   // [4096,4096]
  const float* W    = (const float*)d_in[3];   // [256,256]
  const float* bG   = (const float*)d_in[4];   // [256]

  float* out0    = (float*)d_out;                       // cost_matrix
  float* out_row = out0 + (size_t)N * N;                // alignment[0]
  float* out_col = out0 + 2 * (size_t)N * N;            // alignment[1]

  // ws layout (float units): cnt[4096] vsum[512] tau[4096] beta[1M] alpha[1M]
  //                          candv[2M] candi[2M] y[1]
  int*   cnt   = (int*)d_ws;
  float* vsum  = (float*)d_ws + 4096;
  float* tau   = (float*)d_ws + 4608;
  float* beta  = (float*)d_ws + 8704;
  float* alpha = (float*)d_ws + 8704 + 1048576;
  float* candv = (float*)d_ws + 8704 + 2 * 1048576;
  int*   candi = (int*)d_ws   + 8704 + 4 * 1048576;
  float* ypt   = (float*)d_ws + 8704 + 6 * 1048576;

  hipMemsetAsync(d_ws, 0, (size_t)4608 * 4, stream);

  hipLaunchKernelGGL(k_colcand2, dim3(64, 8), dim3(256), 0, stream, cost, cnt, candv, candi);
  hipLaunchKernelGGL(k_coltau,   dim3(1024),  dim3(256), 0, stream, cnt, candv, candi, rowv, tau, alpha);
  hipLaunchKernelGGL(k_row,      dim3(4096),  dim3(256), 0, stream, cost, colv, tau, out_row, out_col, beta);
  hipLaunchKernelGGL(k_G,        dim3(256,2), dim3(256), 0, stream, beta, alpha, W, bG, vsum);
  hipLaunchKernelGGL(k_final,    dim3(1),     dim3(256), 0, stream, vsum, ypt);
  hipLaunchKernelGGL(k_fill,     dim3(16384), dim3(256), 0, stream, ypt, (float4*)out0);
}

// Round 4
// 351.226 us; speedup vs baseline: 1.2502x; 1.1214x over previous
//
#include <hip/hip_runtime.h>
#include <math.h>

#define N 4096
#define DD 256
#define CAP 512      // per-column candidate capacity (~85 expected)
#define RCAP 256     // per-row support capacity
#define LEAKY 0.2f

// ---------------------------------------------------------------------------
// Pass 1: single-read column candidate compaction, NO SPILL version.
// Block = 256 thr = 16 columns x 16 row-chunks; each thread holds 32 values of
// one column in registers (statically indexed -> stays in VGPRs). 16
// threads/column merge maxes via LDS -> tight 512-row slab threshold.
// tau*_j >= M_j - 1 >= m_slab - 1, so the compacted set is a conservative
// superset of the support (Michelot on a superset is exact).
// ---------------------------------------------------------------------------
__global__ __launch_bounds__(256) void k_colcand2(const float* __restrict__ cost,
      int* __restrict__ cnt, float* __restrict__ candv, int* __restrict__ candi){
  const int tc = threadIdx.x & 15;        // column within block (16)
  const int tr = threadIdx.x >> 4;        // row chunk (16 chunks of 32)
  const int j  = blockIdx.x * 16 + tc;
  const int r0 = blockIdx.y * 512 + tr * 32;
  const float* p = cost + (size_t)r0 * N + j;

  float v[32];
  #pragma unroll
  for (int r = 0; r < 32; ++r) v[r] = -p[(size_t)r * N];

  float m = v[0];
  #pragma unroll
  for (int r = 1; r < 32; ++r) m = fmaxf(m, v[r]);

  __shared__ float smax[16][17];
  smax[tr][tc] = m;
  __syncthreads();
  float m16 = smax[0][tc];
  #pragma unroll
  for (int s = 1; s < 16; ++s) m16 = fmaxf(m16, smax[s][tc]);
  const float th = m16 - 1.0f;

  // ~0.7 candidates expected per thread: atomic per candidate is cheap and
  // avoids any dynamically-indexed private array (which would spill).
  #pragma unroll
  for (int r = 0; r < 32; ++r){
    if (v[r] > th){
      int q = atomicAdd(&cnt[j], 1);
      if (q < CAP){
        candv[(size_t)j * CAP + q] = v[r];
        candi[(size_t)j * CAP + q] = r0 + r;
      }
    }
  }
}

// ---------------------------------------------------------------------------
// Column tau (Michelot on candidates, one wave per column) + alpha[j,:].
// Support compacted into LDS via ballot-prefix; gather loop independent.
// ---------------------------------------------------------------------------
__global__ __launch_bounds__(256) void k_coltau(const int* __restrict__ cnt,
      const float* __restrict__ candv, const int* __restrict__ candi,
      const float* __restrict__ rowvecs, float* __restrict__ tau_out,
      float* __restrict__ alpha){
  const int t = threadIdx.x, w = t >> 6, lane = t & 63;
  const int j = blockIdx.x * 4 + w;
  const int c = min(cnt[j], CAP);
  const float* cv = candv + (size_t)j * CAP;
  const int*   ci = candi + (size_t)j * CAP;

  float v[8]; int id[8];
  #pragma unroll
  for (int s = 0; s < 8; ++s){
    int l = s * 64 + lane;
    v[s]  = (l < c) ? cv[l] : -3.4e38f;
    id[s] = (l < c) ? ci[l] : 0;
  }

  float tau = -3.0e38f;
  for (int it = 0; it < 40; ++it){
    float sum = 0.0f, cf = 0.0f;
    #pragma unroll
    for (int s = 0; s < 8; ++s) if (v[s] > tau){ sum += v[s]; cf += 1.0f; }
    for (int off = 32; off; off >>= 1){ sum += __shfl_xor(sum, off); cf += __shfl_xor(cf, off); }
    float nt = (sum - 1.0f) / cf;
    if (nt == tau) break;
    tau = nt;
  }
  if (lane == 0) tau_out[j] = tau;

  // compact support (p = v - tau > 0) into per-wave LDS
  __shared__ float sup_v[4][CAP];
  __shared__ int   sup_i[4][CAP];
  int base = 0;
  #pragma unroll
  for (int s = 0; s < 8; ++s){
    bool pred = (v[s] > tau);
    unsigned long long mk = __ballot(pred);
    if (pred){
      int pos = base + __popcll(mk & ((1ULL << lane) - 1ULL));
      sup_v[w][pos] = v[s] - tau;
      sup_i[w][pos] = id[s];
    }
    base += __popcll(mk);
  }
  const int ns = base;
  __builtin_amdgcn_wave_barrier();
  __asm__ volatile("s_waitcnt lgkmcnt(0)");

  float a0 = 0, a1 = 0, a2 = 0, a3 = 0;
  #pragma unroll 4
  for (int l = 0; l < ns; ++l){
    float pp = sup_v[w][l];
    const float* ar = rowvecs + (size_t)sup_i[w][l] * DD;
    a0 += pp * ar[lane];        a1 += pp * ar[64 + lane];
    a2 += pp * ar[128 + lane];  a3 += pp * ar[192 + lane];
  }
  float* al = alpha + (size_t)j * DD;
  al[lane] = a0; al[64 + lane] = a1; al[128 + lane] = a2; al[192 + lane] = a3;
}

// ---------------------------------------------------------------------------
// Row sparsemax, FUSED: reads cost row once; writes row_alignment AND
// column_alignment; accumulates beta[i,:].
// ---------------------------------------------------------------------------
__global__ __launch_bounds__(256) void k_row(const float* __restrict__ cost,
      const float* __restrict__ colvecs, const float* __restrict__ tau_col,
      float* __restrict__ out_row, float* __restrict__ out_col,
      float* __restrict__ beta){
  const int i = blockIdx.x, t = threadIdx.x;
  const int w = t >> 6, lane = t & 63;
  __shared__ float s_red[4];
  __shared__ float s_M, s_tau, s_b;
  __shared__ int   s_cnt, s_cnt2;
  __shared__ float s_cv[RCAP];
  __shared__ int   s_cj[RCAP];

  const float4* row4 = (const float4*)(cost + (size_t)i * N);
  const float4* tau4 = (const float4*)tau_col;
  float4 x4[4], tt4[4];
  #pragma unroll
  for (int q = 0; q < 4; ++q){
    float4 v = row4[t + q * 256];
    x4[q] = make_float4(-v.x, -v.y, -v.z, -v.w);
    tt4[q] = tau4[t + q * 256];
  }
  float m = -3.4e38f;
  #pragma unroll
  for (int q = 0; q < 4; ++q)
    m = fmaxf(m, fmaxf(fmaxf(x4[q].x, x4[q].y), fmaxf(x4[q].z, x4[q].w)));
  for (int off = 32; off; off >>= 1) m = fmaxf(m, __shfl_xor(m, off));
  if (lane == 0) s_red[w] = m;
  if (t == 0){ s_cnt = 0; s_cnt2 = 0; }
  __syncthreads();
  if (t == 0) s_M = fmaxf(fmaxf(s_red[0], s_red[1]), fmaxf(s_red[2], s_red[3]));
  __syncthreads();
  const float M = s_M, th = M - 1.0f;

  #pragma unroll
  for (int q = 0; q < 4; ++q){
    const float* e = &x4[q].x;
    #pragma unroll
    for (int c = 0; c < 4; ++c){
      float v = e[c];
      if (v > th){ int p = atomicAdd(&s_cnt, 1); if (p < RCAP) s_cv[p] = v; }
    }
  }
  __syncthreads();
  int c = s_cnt;
  if (c <= RCAP){
    if (w == 0){
      float v[4];
      #pragma unroll
      for (int s = 0; s < 4; ++s){ int l = s * 64 + lane; v[s] = (l < c) ? s_cv[l] : -3.4e38f; }
      float tau = -3.0e38f;
      for (int it = 0; it < 40; ++it){
        float sum = 0.0f, cf = 0.0f;
        #pragma unroll
        for (int s = 0; s < 4; ++s) if (v[s] > tau){ sum += v[s]; cf += 1.0f; }
        for (int off = 32; off; off >>= 1){ sum += __shfl_xor(sum, off); cf += __shfl_xor(cf, off); }
        float nt = (sum - 1.0f) / cf;
        if (nt == tau) break;
        tau = nt;
      }
      if (lane == 0) s_tau = tau;
    }
    __syncthreads();
  } else {
    // fallback: block bisection on [M-1, M] (not taken for this input)
    float lo = th, hi = M;
    for (int it = 0; it < 40; ++it){
      float mid = 0.5f * (lo + hi);
      float part = 0.0f;
      #pragma unroll
      for (int q = 0; q < 4; ++q){
        const float* e = &x4[q].x;
        #pragma unroll
        for (int cc = 0; cc < 4; ++cc) part += fmaxf(e[cc] - mid, 0.0f);
      }
      for (int off = 32; off; off >>= 1) part += __shfl_xor(part, off);
      if (lane == 0) s_red[w] = part;
      __syncthreads();
      if (t == 0) s_b = s_red[0] + s_red[1] + s_red[2] + s_red[3];
      __syncthreads();
      if (s_b >= 1.0f) lo = mid; else hi = mid;
      __syncthreads();
    }
    if (t == 0) s_tau = lo;
    __syncthreads();
  }
  const float tau = s_tau;

  float4* orow4 = (float4*)(out_row + (size_t)i * N);
  float4* ocol4 = (float4*)(out_col + (size_t)i * N);
  #pragma unroll
  for (int q = 0; q < 4; ++q){
    float4 p;
    p.x = fmaxf(x4[q].x - tau, 0.0f);
    p.y = fmaxf(x4[q].y - tau, 0.0f);
    p.z = fmaxf(x4[q].z - tau, 0.0f);
    p.w = fmaxf(x4[q].w - tau, 0.0f);
    orow4[t + q * 256] = p;

    float4 pc;
    pc.x = fmaxf(x4[q].x - tt4[q].x, 0.0f);
    pc.y = fmaxf(x4[q].y - tt4[q].y, 0.0f);
    pc.z = fmaxf(x4[q].z - tt4[q].z, 0.0f);
    pc.w = fmaxf(x4[q].w - tt4[q].w, 0.0f);
    ocol4[t + q * 256] = pc;

    int jb = 4 * (t + q * 256);
    const float* e = &p.x;
    #pragma unroll
    for (int cc = 0; cc < 4; ++cc){
      if (e[cc] > 0.0f){
        int l = atomicAdd(&s_cnt2, 1);
        if (l < RCAP){ s_cv[l] = e[cc]; s_cj[l] = jb + cc; }
      }
    }
  }
  __syncthreads();
  int ns = min(s_cnt2, RCAP);
  float acc = 0.0f;
  #pragma unroll 4
  for (int l = 0; l < ns; ++l)
    acc += s_cv[l] * colvecs[(size_t)s_cj[l] * DD + t];
  beta[(size_t)i * DD + t] = acc;
}

// ---------------------------------------------------------------------------
// G(x) = leaky_relu(x @ W + b); accumulate column sums for the means
// ---------------------------------------------------------------------------
__global__ __launch_bounds__(256) void k_G(const float* __restrict__ beta,
      const float* __restrict__ alpha, const float* __restrict__ W,
      const float* __restrict__ bG, float* __restrict__ vsum){
  int t = threadIdx.x, side = blockIdx.y, r0 = blockIdx.x * 16;
  const float* src = side ? alpha : beta;
  __shared__ float sB[16 * 256];
  #pragma unroll
  for (int k = 0; k < 16; ++k) sB[k * 256 + t] = src[(size_t)(r0 + k) * 256 + t];
  __syncthreads();
  float acc[16];
  float bg = bG[t];
  #pragma unroll
  for (int r = 0; r < 16; ++r) acc[r] = bg;
  const float4* sB4 = (const float4*)sB;
  for (int d4 = 0; d4 < 64; ++d4){
    int d = d4 * 4;
    float w0 = W[(size_t)d * 256 + t];
    float w1 = W[(size_t)(d + 1) * 256 + t];
    float w2 = W[(size_t)(d + 2) * 256 + t];
    float w3 = W[(size_t)(d + 3) * 256 + t];
    #pragma unroll
    for (int r = 0; r < 16; ++r){
      float4 s = sB4[r * 64 + d4];
      acc[r] += s.x * w0 + s.y * w1 + s.z * w2 + s.w * w3;
    }
  }
  float s = 0.0f;
  #pragma unroll
  for (int r = 0; r < 16; ++r){ float u = acc[r]; s += (u > 0.0f) ? u : LEAKY * u; }
  atomicAdd(&vsum[side * 256 + t], s);
}

// cosine cost scalar
__global__ __launch_bounds__(256) void k_final(const float* __restrict__ vsum,
                                               float* __restrict__ y){
  int t = threadIdx.x, w = t >> 6, lane = t & 63;
  __shared__ float rd[3][4];
  float v1 = vsum[t]       * (1.0f / 4096.0f);
  float v2 = vsum[256 + t] * (1.0f / 4096.0f);
  float d = v1 * v2, a = v1 * v1, b = v2 * v2;
  for (int off = 32; off; off >>= 1){
    d += __shfl_xor(d, off); a += __shfl_xor(a, off); b += __shfl_xor(b, off);
  }
  if (lane == 0){ rd[0][w] = d; rd[1][w] = a; rd[2][w] = b; }
  __syncthreads();
  if (t == 0){
    float dd = rd[0][0] + rd[0][1] + rd[0][2] + rd[0][3];
    float aa = rd[1][0] + rd[1][1] + rd[1][2] + rd[1][3];
    float bb = rd[2][0] + rd[2][1] + rd[2][2] + rd[2][3];
    y[0] = 1.0f - dd / (sqrtf(aa) * sqrtf(bb) + 1e-8f);
  }
}

// write-only broadcast of y into out0
__global__ __launch_bounds__(256) void k_fill(const float* __restrict__ ypt,
                                              float4* __restrict__ out0){
  int idx = blockIdx.x * 256 + threadIdx.x;
  float y = ypt[0];
  out0[idx] = make_float4(y, y, y, y);
}

extern "C" void kernel_launch(void* const* d_in, const int* in_sizes, int n_in,
                              void* d_out, int out_size, void* d_ws, size_t ws_size,
                              hipStream_t stream){
  const float* rowv = (const float*)d_in[0];   // [4096,256]
  const float* colv = (const float*)d_in[1];   // [4096,256]
  const float* cost = (const float*)d_in[2];   // [4096,4096]
  const float* W    = (const float*)d_in[3];   // [256,256]
  const float* bG   = (const float*)d_in[4];   // [256]

  float* out0    = (float*)d_out;
  float* out_row = out0 + (size_t)N * N;
  float* out_col = out0 + 2 * (size_t)N * N;

  int*   cnt   = (int*)d_ws;
  float* vsum  = (float*)d_ws + 4096;
  float* tau   = (float*)d_ws + 4608;
  float* beta  = (float*)d_ws + 8704;
  float* alpha = (float*)d_ws + 8704 + 1048576;
  float* candv = (float*)d_ws + 8704 + 2 * 1048576;
  int*   candi = (int*)d_ws   + 8704 + 4 * 1048576;
  float* ypt   = (float*)d_ws + 8704 + 6 * 1048576;

  hipMemsetAsync(d_ws, 0, (size_t)4608 * 4, stream);

  hipLaunchKernelGGL(k_colcand2, dim3(256, 8), dim3(256), 0, stream, cost, cnt, candv, candi);
  hipLaunchKernelGGL(k_coltau,   dim3(1024),   dim3(256), 0, stream, cnt, candv, candi, rowv, tau, alpha);
  hipLaunchKernelGGL(k_row,      dim3(4096),   dim3(256), 0, stream, cost, colv, tau, out_row, out_col, beta);
  hipLaunchKernelGGL(k_G,        dim3(256,2),  dim3(256), 0, stream, beta, alpha, W, bG, vsum);
  hipLaunchKernelGGL(k_final,    dim3(1),      dim3(256), 0, stream, vsum, ypt);
  hipLaunchKernelGGL(k_fill,     dim3(16384),  dim3(256), 0, stream, ypt, (float4*)out0);
}